// Round 2
// baseline (108.254 us; speedup 1.0000x reference)
//
#include <hip/hip_runtime.h>

#define CINC 64
#define COUT 64
#define HH 32
#define WW 32
#define BB 16

typedef __attribute__((ext_vector_type(8))) short short8;
typedef __attribute__((ext_vector_type(4))) float floatx4;

__device__ __forceinline__ unsigned short f2bf(float f) {
    union { float f; unsigned int u; } c; c.f = f;
    unsigned int r = (c.u + 0x7FFFu + ((c.u >> 16) & 1u)) >> 16;
    return (unsigned short)r;
}

// W3 layout: [tap(9)][s(16)][oc(64)][q(4)][e(8)] bf16, linear in g = tap*16 + s
// k = s*32 + q*8 + e (0..511), cin = s*4+q, basis index = e
__global__ __launch_bounds__(256) void wt_kernel(const float* __restrict__ sw,
                                                 const float* __restrict__ sc,
                                                 short* __restrict__ W3) {
    int idx = blockIdx.x * blockDim.x + threadIdx.x;
    const int total = 9 * 16 * 64 * 4 * 8;           // 294,912
    if (idx >= total) return;
    int e = idx & 7;
    int q = (idx >> 3) & 3;
    int oc = (idx >> 5) & 63;
    int s = (idx >> 11) & 15;
    int tap = idx >> 15;                              // 0..8
    int cin = s * 4 + q;
    int g = e;
    int kh = tap / 3, kw = tap % 3;
    float w = sw[(((oc * CINC + cin) * 8 + g) * 3 + kh) * 3 + kw] * sc[oc * CINC + cin];
    W3[idx] = (short)f2bf(w);
}

// Fused bases + full-Cin implicit-GEMM conv, direct output write.
// Grid: 256 m-blocks (b, row-pair). Block: 8 waves (512 thr), 2 waves/SIMD.
// Wave = (rowl, xhalf, ochalf): mt=1, nt=2.
// B-loads: explicit DEPTH-8 register pipeline (16 loads in flight per wave) to
// cover the ~200-cyc L2-hit latency (round-1 counters: 441 cyc/SIMD-step with
// depth-1 prefetch => latency-bound). All pipeline indices compile-time
// (slot = s&7 inside the unrolled-16 inner loop) -> registers, no scratch.
__global__ __launch_bounds__(512, 2) void conv_kernel(const float* __restrict__ xin,
                                                      const short* __restrict__ W3,
                                                      float* __restrict__ out) {
    __shared__ short A[4 * 34 * 512];   // [r(4)][x(34)][slot(64)][e(8)], slot = cin ^ (x&15)

    const int mb = blockIdx.x;
    const int b = mb >> 4;
    const int h0 = (mb & 15) * 2;
    const int t = threadIdx.x;
    const int wave = t >> 6;
    const int lane = t & 63;
    const int l15 = lane & 15;
    const int q = lane >> 4;
    const int xh = (wave & 1) * 16;       // x-half of the row (mt split)
    const int rowl = (wave >> 1) & 1;     // output row within the pair
    const int n0 = (wave >> 2) * 32;      // oc-half

    // ---- B pipeline prologue: issue first 8 steps' loads (overlaps staging) ----
    const short* wb = W3 + (n0 + l15) * 32 + q * 8;
    short8 pb0[8], pb1[8];
#pragma unroll
    for (int g = 0; g < 8; ++g) {
        pb0[g] = *(const short8*)(wb + g * 2048);
        pb1[g] = *(const short8*)(wb + g * 2048 + 512);
    }

    // ---- stage A: closed-form uniform cubic B-spline bases -> bf16 LDS ----
    for (int u = t; u < 4 * 34 * CINC; u += 512) {    // 8704 items, 17 iters, x-innermost
        int x34 = u % 34;
        int rc = u / 34;
        int cl = rc & 63;
        int r = rc >> 6;
        int y = h0 + r;
        float v = 0.0f;
        if (y >= 1 && y <= HH && x34 >= 1 && x34 <= WW)
            v = xin[((b * CINC + cl) * HH + (y - 1)) * WW + (x34 - 1)];
        float sv = fmaf(v, 2.5f, 5.5f);               // (v + 2.2) / 0.4
        float cf = floorf(sv);
        int c = (int)cf;
        float f = sv - cf;
        float f2 = f * f, f3 = f2 * f;
        float omf = 1.0f - f;
        float w0 = f3 * (1.0f / 6.0f);
        float w1 = (1.0f + 3.0f * f + 3.0f * f2 - 3.0f * f3) * (1.0f / 6.0f);
        float w2 = (4.0f - 6.0f * f2 + 3.0f * f3) * (1.0f / 6.0f);
        float w3 = (omf * omf * omf) * (1.0f / 6.0f);
        short o8[8];
#pragma unroll
        for (int j = 0; j < 8; ++j) {
            float bj = (j == c) ? w0 : (j == c - 1) ? w1 : (j == c - 2) ? w2
                       : (j == c - 3) ? w3 : 0.0f;
            o8[j] = (short)f2bf(bj);
        }
        *(int4*)&A[(r * 34 + x34) * 512 + ((cl ^ (x34 & 15)) * 8)] = *(const int4*)o8;
    }
    __syncthreads();

    floatx4 acc0 = (floatx4)0.f, acc1 = (floatx4)0.f;

    // ---- main loop: 144 steps = 9 taps x 16 k-sixteenths, depth-8 B pipeline ----
    // Load for global step g lands in slot g&7, consumed 8 steps later; 16 steps
    // per tap is a multiple of 8, so the phase is tap-invariant. The final 8
    // prefetches read the 32 KB slack after W3 (registers only, never consumed,
    // never touched by FP ops - safe with poisoned workspace).
    for (int tap = 0; tap < 9; ++tap) {
        const int kh = tap / 3, kw = tap % 3;
        const int x15 = (l15 + kw) & 15;
        const int abase = ((rowl + kh) * 34 + xh + l15 + kw) * 512;
        const short* wt = wb + (tap * 16 + 8) * 2048;
#pragma unroll
        for (int s = 0; s < 16; ++s) {
            const int slot = s & 7;                    // compile-time in unrolled body
            short8 b0 = pb0[slot];
            short8 b1 = pb1[slot];
            pb0[slot] = *(const short8*)(wt + s * 2048);
            pb1[slot] = *(const short8*)(wt + s * 2048 + 512);
            short8 aF = *(const short8*)&A[abase + (((s * 4 + q) ^ x15) * 8)];
            acc0 = __builtin_amdgcn_mfma_f32_16x16x32_bf16(aF, b0, acc0, 0, 0, 0);
            acc1 = __builtin_amdgcn_mfma_f32_16x16x32_bf16(aF, b1, acc1, 0, 0, 0);
        }
    }

    // ---- epilogue: direct float4 stores to out ----
    const int h = h0 + rowl;
    {
        const int oc0 = n0 + l15;
        float* op0 = out + (((size_t)b * COUT + oc0) * HH + h) * WW + xh + q * 4;
        *(floatx4*)op0 = acc0;
        const int oc1 = n0 + 16 + l15;
        float* op1 = out + (((size_t)b * COUT + oc1) * HH + h) * WW + xh + q * 4;
        *(floatx4*)op1 = acc1;
    }
}

extern "C" void kernel_launch(void* const* d_in, const int* in_sizes, int n_in,
                              void* d_out, int out_size, void* d_ws, size_t ws_size,
                              hipStream_t stream) {
    const float* x  = (const float*)d_in[0];
    const float* sw = (const float*)d_in[1];
    const float* sc = (const float*)d_in[2];
    float* out = (float*)d_out;
    short* W3 = (short*)d_ws;   // 294,912 bf16 = 576 KB (+32 KB prefetch slack)

    wt_kernel<<<(294912 + 255) / 256, 256, 0, stream>>>(sw, sc, W3);
    conv_kernel<<<256, 512, 0, stream>>>(x, W3, out);
}

// Round 3
// 85.961 us; speedup vs baseline: 1.2593x; 1.2593x over previous
//
#include <hip/hip_runtime.h>

#define CINC 64
#define COUT 64
#define HH 32
#define WW 32
#define BB 16
#define NSPLIT 4
#define CPS 16            // cin per split

typedef __attribute__((ext_vector_type(8))) short short8;
typedef __attribute__((ext_vector_type(4))) float floatx4;

__device__ __forceinline__ unsigned short f2bf(float f) {
    union { float f; unsigned int u; } c; c.f = f;
    unsigned int r = (c.u + 0x7FFFu + ((c.u >> 16) & 1u)) >> 16;
    return (unsigned short)r;
}

// W3 layout (round-0, verified): [split(4)][tap(9)][s(4)][oc(64)][q(4)][e(8)] bf16
// k = s*32 + q*8 + e (0..127), cin = split*16 + k/8, g = k%8
__global__ __launch_bounds__(256) void wt_kernel(const float* __restrict__ sw,
                                                 const float* __restrict__ sc,
                                                 short* __restrict__ W3) {
    int idx = blockIdx.x * blockDim.x + threadIdx.x;
    const int total = NSPLIT * 9 * 4 * 64 * 4 * 8;   // 294,912
    if (idx >= total) return;
    int e = idx & 7;
    int q = (idx >> 3) & 3;
    int oc = (idx >> 5) & 63;
    int s = (idx >> 11) & 3;
    int tap = (idx >> 13) % 9;
    int split = (idx >> 13) / 9;
    int k = s * 32 + q * 8 + e;
    int cin = split * CPS + (k >> 3);
    int g = k & 7;
    int kh = tap / 3, kw = tap % 3;
    float w = sw[(((oc * CINC + cin) * 8 + g) * 3 + kh) * 3 + kw] * sc[oc * CINC + cin];
    W3[idx] = (short)f2bf(w);
}

// Fused bases + implicit-GEMM conv with IN-BLOCK cin-split reduction.
// Grid: 256 blocks (b, row-pair). Block: 1024 thr = 16 waves = 4 waves/SIMD
// (round-0's TLP, which hid the depth-1 B-load latency). Wave = (split = w&3,
// rowl = (w>>2)&1, oc-half = w>>3); per wave: mt=2, nt=2, 36 k-steps — the
// verified round-0 main loop with a per-split LDS base. Epilogue: 4-way
// cross-split reduce through LDS (aliases A after barrier), direct out write.
// No reduce kernel, no 32 MB partial round-trip.
__global__ __launch_bounds__(1024, 4) void conv_kernel(const float* __restrict__ xin,
                                                       const short* __restrict__ W3,
                                                       float* __restrict__ out) {
    __shared__ __align__(16) char smem[139264];
    short* A = (short*)smem;   // [split][r(4)][x(34)][slot(16)][e(8)], slot = cl^(x&15)
    float* P = (float*)smem;   // [split][row(128) = rowl*64+ocl][stride 36][x(32)]

    const int mb = blockIdx.x;
    const int b = mb >> 4;
    const int h0 = (mb & 15) * 2;
    const int t = threadIdx.x;
    const int wave = t >> 6;
    const int lane = t & 63;
    const int l15 = lane & 15;
    const int q = lane >> 4;
    const int split = wave & 3;
    const int rowl = (wave >> 2) & 1;
    const int n0 = (wave >> 3) * 32;

    // ---- prefetch first B fragments (no LDS dependency, overlaps staging) ----
    const short* Wb = W3 + (size_t)split * 36 * 2048;
    short8 bq[2], bqn[2];
#pragma unroll
    for (int nt = 0; nt < 2; ++nt)
        bqn[nt] = *(const short8*)(Wb + (n0 + nt * 16 + l15) * 32 + q * 8);

    // ---- stage A: closed-form uniform cubic B-spline bases -> bf16 LDS ----
    // 8704 items (4 rows x 34 x x 64 cin), x-innermost for coalescing.
    for (int u = t; u < 4 * 34 * CINC; u += 1024) {
        int x34 = u % 34;
        int rc = u / 34;                 // 0..255
        int c6 = rc & 63;                // cin 0..63
        int r = rc >> 6;
        int sp = c6 >> 4;                // which split's tile
        int cl = c6 & 15;
        int y = h0 + r;
        float v = 0.0f;
        if (y >= 1 && y <= HH && x34 >= 1 && x34 <= WW)
            v = xin[((b * CINC + c6) * HH + (y - 1)) * WW + (x34 - 1)];
        float sv = fmaf(v, 2.5f, 5.5f);               // (v + 2.2) / 0.4
        float cf = floorf(sv);
        int c = (int)cf;
        float f = sv - cf;
        float f2 = f * f, f3 = f2 * f;
        float omf = 1.0f - f;
        float w0 = f3 * (1.0f / 6.0f);
        float w1 = (1.0f + 3.0f * f + 3.0f * f2 - 3.0f * f3) * (1.0f / 6.0f);
        float w2 = (4.0f - 6.0f * f2 + 3.0f * f3) * (1.0f / 6.0f);
        float w3 = (omf * omf * omf) * (1.0f / 6.0f);
        short o8[8];
#pragma unroll
        for (int j = 0; j < 8; ++j) {
            float bj = (j == c) ? w0 : (j == c - 1) ? w1 : (j == c - 2) ? w2
                       : (j == c - 3) ? w3 : 0.0f;
            o8[j] = (short)f2bf(bj);
        }
        *(int4*)&A[sp * 17408 + (r * 34 + x34) * 128 + ((cl ^ (x34 & 15)) * 8)] =
            *(const int4*)o8;
    }
    __syncthreads();

    floatx4 acc[2][2];
#pragma unroll
    for (int mt = 0; mt < 2; ++mt)
#pragma unroll
        for (int nt = 0; nt < 2; ++nt) acc[mt][nt] = (floatx4)0.f;

    const int abase = split * 17408;

    // ---- main loop: 36 steps = 9 taps x 4 k-quarters, 1-step B prefetch ----
#pragma unroll
    for (int ts = 0; ts < 36; ++ts) {
        const int tap = ts >> 2, s = ts & 3;
        const int kh = tap / 3, kw = tap % 3;
#pragma unroll
        for (int nt = 0; nt < 2; ++nt) bq[nt] = bqn[nt];
        if (ts < 35) {
            const short* wp = Wb + (size_t)(ts + 1) * 2048;
#pragma unroll
            for (int nt = 0; nt < 2; ++nt)
                bqn[nt] = *(const short8*)(wp + (n0 + nt * 16 + l15) * 32 + q * 8);
        }
#pragma unroll
        for (int mt = 0; mt < 2; ++mt) {
            const int xi = mt * 16 + l15 + kw;
            short8 aF = *(const short8*)&A[abase + ((rowl + kh) * 34 + xi) * 128 +
                                           (((s * 4 + q) ^ (xi & 15)) * 8)];
#pragma unroll
            for (int nt = 0; nt < 2; ++nt)
                acc[mt][nt] = __builtin_amdgcn_mfma_f32_16x16x32_bf16(aF, bq[nt], acc[mt][nt], 0, 0, 0);
        }
    }

    // ---- epilogue: cross-split reduce via LDS, then direct out write ----
    __syncthreads();   // all A reads done; safe to alias with P
#pragma unroll
    for (int mt = 0; mt < 2; ++mt) {
#pragma unroll
        for (int nt = 0; nt < 2; ++nt) {
            const int row = rowl * 64 + n0 + nt * 16 + l15;   // 0..127
            // stride 36 floats (144 B): 16B-aligned float4 slots, banks spread
            *(floatx4*)(P + split * 4608 + row * 36 + mt * 16 + q * 4) = acc[mt][nt];
        }
    }
    __syncthreads();
    {
        const int x4 = (t & 7) * 4;        // 0..28
        const int row = t >> 3;            // 0..127 = rowl*64 + ocl
        const int ocl = row & 63;
        const int hh = h0 + (row >> 6);
        const int po = row * 36 + x4;
        floatx4 v = *(const floatx4*)(P + po)
                  + *(const floatx4*)(P + 4608 + po)
                  + *(const floatx4*)(P + 2 * 4608 + po)
                  + *(const floatx4*)(P + 3 * 4608 + po);
        *(floatx4*)(out + (((size_t)b * COUT + ocl) * HH + hh) * WW + x4) = v;
    }
}

extern "C" void kernel_launch(void* const* d_in, const int* in_sizes, int n_in,
                              void* d_out, int out_size, void* d_ws, size_t ws_size,
                              hipStream_t stream) {
    const float* x  = (const float*)d_in[0];
    const float* sw = (const float*)d_in[1];
    const float* sc = (const float*)d_in[2];
    float* out = (float*)d_out;
    short* W3 = (short*)d_ws;                           // 294,912 bf16 = 576 KB

    wt_kernel<<<(294912 + 255) / 256, 256, 0, stream>>>(sw, sc, W3);
    conv_kernel<<<256, 1024, 0, stream>>>(x, W3, out);
}

// Round 5
// 85.739 us; speedup vs baseline: 1.2626x; 1.0026x over previous
//
#include <hip/hip_runtime.h>

#define CINC 64
#define COUT 64
#define HH 32
#define WW 32
#define BB 16
#define NSPLIT 4
#define CPS 16            // cin per split

typedef __attribute__((ext_vector_type(8))) short short8;
typedef __attribute__((ext_vector_type(4))) float floatx4;

__device__ __forceinline__ unsigned short f2bf(float f) {
    union { float f; unsigned int u; } c; c.f = f;
    unsigned int r = (c.u + 0x7FFFu + ((c.u >> 16) & 1u)) >> 16;
    return (unsigned short)r;
}

// W3 layout (verified): [split(4)][tap(9)][s(4)][oc(64)][q(4)][e(8)] bf16
// k = s*32 + q*8 + e (0..127), cin = split*16 + k/8, g = k%8
__global__ __launch_bounds__(256) void wt_kernel(const float* __restrict__ sw,
                                                 const float* __restrict__ sc,
                                                 short* __restrict__ W3) {
    int idx = blockIdx.x * blockDim.x + threadIdx.x;
    const int total = NSPLIT * 9 * 4 * 64 * 4 * 8;   // 294,912
    if (idx >= total) return;
    int e = idx & 7;
    int q = (idx >> 3) & 3;
    int oc = (idx >> 5) & 63;
    int s = (idx >> 11) & 3;
    int tap = (idx >> 13) % 9;
    int split = (idx >> 13) / 9;
    int k = s * 32 + q * 8 + e;
    int cin = split * CPS + (k >> 3);
    int g = k & 7;
    int kh = tap / 3, kw = tap % 3;
    float w = sw[(((oc * CINC + cin) * 8 + g) * 3 + kh) * 3 + kw] * sc[oc * CINC + cin];
    W3[idx] = (short)f2bf(w);
}

// Counted-vmcnt wait tied to the slot being consumed (true data-dep orders the
// MFMAs after the wait; volatile order pins the pipeline shape).
#define VM_WAIT(N, a, b) asm volatile("s_waitcnt vmcnt(" #N ")" : "+v"(a), "+v"(b))
// Issue one step's two B-fragment loads. Early-clobber: dests never alias addr.
#define B_ISSUE(a, b, p)                                            \
    asm volatile("global_load_dwordx4 %0, %2, off\n\t"              \
                 "global_load_dwordx4 %1, %2, off offset:1024"      \
                 : "=&v"(a), "=&v"(b) : "v"(p))

// Fused bases + implicit-GEMM conv with in-block cin-split reduction.
// Grid: 256 blocks (b, row-pair). Block: 1024 thr = 16 waves = 4 waves/SIMD.
// Wave = (split = w&3, rowl = (w>>2)&1, oc-half = w>>3); mt=2, nt=2, 36 k-steps.
// B pipeline: depth-4 (8 loads in flight), EVERY issued load is consumed —
// prologue issues steps 0..3; taps 0..7 wait vmcnt(6)+issue ts+4; tap 8 drains
// with descending waits 6/4/2/0 and issues nothing. No in-flight loads survive
// the loop (round-4 crash mechanism: tail loads landing in reallocated VGPRs).
__global__ __launch_bounds__(1024, 4) void conv_kernel(const float* __restrict__ xin,
                                                       const short* __restrict__ W3,
                                                       float* __restrict__ out) {
    __shared__ __align__(16) char smem[139264];
    short* A = (short*)smem;   // [split][r(4)][x(34)][slot(16)][e(8)], slot = cl^(x&15)
    float* P = (float*)smem;   // [split][row(128) = rowl*64+ocl][stride 36][x(32)]

    const int mb = blockIdx.x;
    const int b = mb >> 4;
    const int h0 = (mb & 15) * 2;
    const int t = threadIdx.x;
    const int wave = t >> 6;
    const int lane = t & 63;
    const int l15 = lane & 15;
    const int q = lane >> 4;
    const int split = wave & 3;
    const int rowl = (wave >> 2) & 1;
    const int n0 = (wave >> 3) * 32;

    // ---- B pipeline prologue: issue steps 0..3 (hides under staging) ----
    const short* Wb = W3 + (size_t)split * 36 * 2048;
    const short* bp = Wb + (n0 + l15) * 32 + q * 8;
    short8 pb0[4], pb1[4];
#pragma unroll
    for (int g = 0; g < 4; ++g) {
        B_ISSUE(pb0[g], pb1[g], bp);
        bp += 2048;
    }

    // ---- stage A: closed-form uniform cubic B-spline bases -> bf16 LDS ----
    for (int u = t; u < 4 * 34 * CINC; u += 1024) {
        int x34 = u % 34;
        int rc = u / 34;                 // 0..255
        int c6 = rc & 63;                // cin 0..63
        int r = rc >> 6;
        int sp = c6 >> 4;                // which split's tile
        int cl = c6 & 15;
        int y = h0 + r;
        float v = 0.0f;
        if (y >= 1 && y <= HH && x34 >= 1 && x34 <= WW)
            v = xin[((b * CINC + c6) * HH + (y - 1)) * WW + (x34 - 1)];
        float sv = fmaf(v, 2.5f, 5.5f);               // (v + 2.2) / 0.4
        float cf = floorf(sv);
        int c = (int)cf;
        float f = sv - cf;
        float f2 = f * f, f3 = f2 * f;
        float omf = 1.0f - f;
        float w0 = f3 * (1.0f / 6.0f);
        float w1 = (1.0f + 3.0f * f + 3.0f * f2 - 3.0f * f3) * (1.0f / 6.0f);
        float w2 = (4.0f - 6.0f * f2 + 3.0f * f3) * (1.0f / 6.0f);
        float w3 = (omf * omf * omf) * (1.0f / 6.0f);
        short o8[8];
#pragma unroll
        for (int j = 0; j < 8; ++j) {
            float bj = (j == c) ? w0 : (j == c - 1) ? w1 : (j == c - 2) ? w2
                       : (j == c - 3) ? w3 : 0.0f;
            o8[j] = (short)f2bf(bj);
        }
        *(int4*)&A[sp * 17408 + (r * 34 + x34) * 128 + ((cl ^ (x34 & 15)) * 8)] =
            *(const int4*)o8;
    }
    __syncthreads();

    floatx4 acc[2][2];
#pragma unroll
    for (int mt = 0; mt < 2; ++mt)
#pragma unroll
        for (int nt = 0; nt < 2; ++nt) acc[mt][nt] = (floatx4)0.f;

    const int abase = split * 17408;

#define DO_MFMAS(B0, B1)                                                        \
    _Pragma("unroll")                                                           \
    for (int mt = 0; mt < 2; ++mt) {                                            \
        const int xi = mt * 16 + l15 + kw;                                      \
        short8 aF = *(const short8*)&A[abase + ((rowl + kh) * 34 + xi) * 128 +  \
                                       (((s * 4 + q) ^ (xi & 15)) * 8)];        \
        acc[mt][0] = __builtin_amdgcn_mfma_f32_16x16x32_bf16(aF, B0, acc[mt][0], 0, 0, 0); \
        acc[mt][1] = __builtin_amdgcn_mfma_f32_16x16x32_bf16(aF, B1, acc[mt][1], 0, 0, 0); \
    }

    // ---- main loop taps 0..7: wait vmcnt(6) -> consume slot s -> issue ts+4 ----
#pragma unroll
    for (int tap = 0; tap < 8; ++tap) {
        const int kh = tap / 3, kw = tap % 3;
#pragma unroll
        for (int s = 0; s < 4; ++s) {
            VM_WAIT(6, pb0[s], pb1[s]);
            short8 b0 = pb0[s];
            short8 b1 = pb1[s];
            B_ISSUE(pb0[s], pb1[s], bp);
            bp += 2048;
            DO_MFMAS(b0, b1)
        }
    }
    // ---- tap 8: drain with descending counted waits, no new issues ----
    {
        const int kh = 2, kw = 2;
        {   const int s = 0; VM_WAIT(6, pb0[0], pb1[0]);
            short8 b0 = pb0[0], b1 = pb1[0]; DO_MFMAS(b0, b1) }
        {   const int s = 1; VM_WAIT(4, pb0[1], pb1[1]);
            short8 b0 = pb0[1], b1 = pb1[1]; DO_MFMAS(b0, b1) }
        {   const int s = 2; VM_WAIT(2, pb0[2], pb1[2]);
            short8 b0 = pb0[2], b1 = pb1[2]; DO_MFMAS(b0, b1) }
        {   const int s = 3; VM_WAIT(0, pb0[3], pb1[3]);
            short8 b0 = pb0[3], b1 = pb1[3]; DO_MFMAS(b0, b1) }
    }
#undef DO_MFMAS

    // ---- epilogue: cross-split reduce via LDS, then direct out write ----
    __syncthreads();   // all A reads done; safe to alias with P
#pragma unroll
    for (int mt = 0; mt < 2; ++mt) {
#pragma unroll
        for (int nt = 0; nt < 2; ++nt) {
            const int row = rowl * 64 + n0 + nt * 16 + l15;   // 0..127
            // stride 36 floats (144 B): 16B-aligned float4 slots, banks spread
            *(floatx4*)(P + split * 4608 + row * 36 + mt * 16 + q * 4) = acc[mt][nt];
        }
    }
    __syncthreads();
    {
        const int x4 = (t & 7) * 4;        // 0..28
        const int row = t >> 3;            // 0..127 = rowl*64 + ocl
        const int ocl = row & 63;
        const int hh = h0 + (row >> 6);
        const int po = row * 36 + x4;
        floatx4 v = *(const floatx4*)(P + po)
                  + *(const floatx4*)(P + 4608 + po)
                  + *(const floatx4*)(P + 2 * 4608 + po)
                  + *(const floatx4*)(P + 3 * 4608 + po);
        *(floatx4*)(out + (((size_t)b * COUT + ocl) * HH + hh) * WW + x4) = v;
    }
}

extern "C" void kernel_launch(void* const* d_in, const int* in_sizes, int n_in,
                              void* d_out, int out_size, void* d_ws, size_t ws_size,
                              hipStream_t stream) {
    const float* x  = (const float*)d_in[0];
    const float* sw = (const float*)d_in[1];
    const float* sc = (const float*)d_in[2];
    float* out = (float*)d_out;
    short* W3 = (short*)d_ws;                           // 294,912 bf16 = 576 KB

    wt_kernel<<<(294912 + 255) / 256, 256, 0, stream>>>(sw, sc, W3);
    conv_kernel<<<256, 1024, 0, stream>>>(x, W3, out);
}

// Round 6
// 80.232 us; speedup vs baseline: 1.3493x; 1.0686x over previous
//
#include <hip/hip_runtime.h>

#define CINC 64
#define COUT 64
#define HH 32
#define WW 32
#define BB 16
#define NSPLIT 4
#define CPS 16            // cin per split

typedef __attribute__((ext_vector_type(8))) short short8;
typedef __attribute__((ext_vector_type(4))) float floatx4;

__device__ __forceinline__ unsigned short f2bf(float f) {
    union { float f; unsigned int u; } c; c.f = f;
    unsigned int r = (c.u + 0x7FFFu + ((c.u >> 16) & 1u)) >> 16;
    return (unsigned short)r;
}

// W3 layout (COALESCED): [split(4)][ts(36)][half(2)][nt(2)][q(4)][l15(16)][e(8)]
// Per (split,ts,half,nt) fragment, lane (q,l15) reads shorts [lane*8 .. lane*8+7]
// -> one fully-contiguous 1 KB wave read (16 cache lines), vs the old
// [oc][q][e] layout where lanes read 16 B at stride 64 B (64 lines, 4x L2
// over-fetch -> saturated per-XCD L2 at ~5.3 TB/s; rounds 3/5 nulls).
// Logical element at idx: ts=tap*4+s, oc=half*32+nt*16+l15, k=s*32+q*8+e,
// cin=split*16+s*4+q, basis g=e.
__global__ __launch_bounds__(256) void wt_kernel(const float* __restrict__ sw,
                                                 const float* __restrict__ sc,
                                                 short* __restrict__ W3) {
    int idx = blockIdx.x * blockDim.x + threadIdx.x;
    const int total = NSPLIT * 36 * 2 * 2 * 4 * 16 * 8;   // 294,912
    if (idx >= total) return;
    int e    = idx & 7;
    int l15  = (idx >> 3) & 15;
    int q    = (idx >> 7) & 3;
    int nt   = (idx >> 9) & 1;
    int half = (idx >> 10) & 1;
    int tsid = idx >> 11;            // 0..143 = split*36 + ts
    int ts   = tsid % 36;
    int split = tsid / 36;
    int s = ts & 3, tap = ts >> 2;
    int oc = half * 32 + nt * 16 + l15;
    int cin = split * CPS + s * 4 + q;
    int g = e;
    int kh = tap / 3, kw = tap % 3;
    float w = sw[(((oc * CINC + cin) * 8 + g) * 3 + kh) * 3 + kw] * sc[oc * CINC + cin];
    W3[idx] = (short)f2bf(w);
}

// Counted-vmcnt wait tied to the slot being consumed (true data-dep orders the
// MFMAs after the wait; volatile order pins the pipeline shape).
#define VM_WAIT(N, a, b) asm volatile("s_waitcnt vmcnt(" #N ")" : "+v"(a), "+v"(b))
// Issue one step's two B-fragment loads (nt=0 at p, nt=1 at p+1024 B).
// Early-clobber: dests never alias the address register pair.
#define B_ISSUE(a, b, p)                                            \
    asm volatile("global_load_dwordx4 %0, %2, off\n\t"              \
                 "global_load_dwordx4 %1, %2, off offset:1024"      \
                 : "=&v"(a), "=&v"(b) : "v"(p))

// Fused bases + implicit-GEMM conv with in-block cin-split reduction.
// Grid: 256 blocks (b, row-pair). Block: 1024 thr = 16 waves = 4 waves/SIMD.
// Wave = (split = w&3, rowl = (w>>2)&1, oc-half = w>>3); mt=2, nt=2, 36 k-steps.
// B pipeline: depth-4 (8 loads in flight), every issued load consumed; B reads
// now fully coalesced (1 KB/wave-load, lane*16 B) -> L2 traffic cut 4x.
__global__ __launch_bounds__(1024, 4) void conv_kernel(const float* __restrict__ xin,
                                                       const short* __restrict__ W3,
                                                       float* __restrict__ out) {
    __shared__ __align__(16) char smem[139264];
    short* A = (short*)smem;   // [split][r(4)][x(34)][slot(16)][e(8)], slot = cl^(x&15)
    float* P = (float*)smem;   // [split][row(128) = rowl*64+ocl][stride 36][x(32)]

    const int mb = blockIdx.x;
    const int b = mb >> 4;
    const int h0 = (mb & 15) * 2;
    const int t = threadIdx.x;
    const int wave = t >> 6;
    const int lane = t & 63;
    const int l15 = lane & 15;
    const int q = lane >> 4;
    const int split = wave & 3;
    const int rowl = (wave >> 2) & 1;
    const int n0 = (wave >> 3) * 32;

    // ---- B pipeline prologue: issue steps 0..3 (hides under staging) ----
    // bp for step ts: W3 + split*73728 + half*1024 + ts*2048 + lane*8 (shorts).
    const short* bp = W3 + (size_t)split * 73728 + (size_t)(wave >> 3) * 1024
                      + lane * 8;
    short8 pb0[4], pb1[4];
#pragma unroll
    for (int g = 0; g < 4; ++g) {
        B_ISSUE(pb0[g], pb1[g], bp);
        bp += 2048;
    }

    // ---- stage A: closed-form uniform cubic B-spline bases -> bf16 LDS ----
    for (int u = t; u < 4 * 34 * CINC; u += 1024) {
        int x34 = u % 34;
        int rc = u / 34;                 // 0..255
        int c6 = rc & 63;                // cin 0..63
        int r = rc >> 6;
        int sp = c6 >> 4;                // which split's tile
        int cl = c6 & 15;
        int y = h0 + r;
        float v = 0.0f;
        if (y >= 1 && y <= HH && x34 >= 1 && x34 <= WW)
            v = xin[((b * CINC + c6) * HH + (y - 1)) * WW + (x34 - 1)];
        float sv = fmaf(v, 2.5f, 5.5f);               // (v + 2.2) / 0.4
        float cf = floorf(sv);
        int c = (int)cf;
        float f = sv - cf;
        float f2 = f * f, f3 = f2 * f;
        float omf = 1.0f - f;
        float w0 = f3 * (1.0f / 6.0f);
        float w1 = (1.0f + 3.0f * f + 3.0f * f2 - 3.0f * f3) * (1.0f / 6.0f);
        float w2 = (4.0f - 6.0f * f2 + 3.0f * f3) * (1.0f / 6.0f);
        float w3 = (omf * omf * omf) * (1.0f / 6.0f);
        short o8[8];
#pragma unroll
        for (int j = 0; j < 8; ++j) {
            float bj = (j == c) ? w0 : (j == c - 1) ? w1 : (j == c - 2) ? w2
                       : (j == c - 3) ? w3 : 0.0f;
            o8[j] = (short)f2bf(bj);
        }
        *(int4*)&A[sp * 17408 + (r * 34 + x34) * 128 + ((cl ^ (x34 & 15)) * 8)] =
            *(const int4*)o8;
    }
    __syncthreads();

    floatx4 acc[2][2];
#pragma unroll
    for (int mt = 0; mt < 2; ++mt)
#pragma unroll
        for (int nt = 0; nt < 2; ++nt) acc[mt][nt] = (floatx4)0.f;

    const int abase = split * 17408;

#define DO_MFMAS(B0, B1)                                                        \
    _Pragma("unroll")                                                           \
    for (int mt = 0; mt < 2; ++mt) {                                            \
        const int xi = mt * 16 + l15 + kw;                                      \
        short8 aF = *(const short8*)&A[abase + ((rowl + kh) * 34 + xi) * 128 +  \
                                       (((s * 4 + q) ^ (xi & 15)) * 8)];        \
        acc[mt][0] = __builtin_amdgcn_mfma_f32_16x16x32_bf16(aF, B0, acc[mt][0], 0, 0, 0); \
        acc[mt][1] = __builtin_amdgcn_mfma_f32_16x16x32_bf16(aF, B1, acc[mt][1], 0, 0, 0); \
    }

    // ---- main loop taps 0..7: wait vmcnt(6) -> consume slot s -> issue ts+4 ----
#pragma unroll
    for (int tap = 0; tap < 8; ++tap) {
        const int kh = tap / 3, kw = tap % 3;
#pragma unroll
        for (int s = 0; s < 4; ++s) {
            VM_WAIT(6, pb0[s], pb1[s]);
            short8 b0 = pb0[s];
            short8 b1 = pb1[s];
            B_ISSUE(pb0[s], pb1[s], bp);
            bp += 2048;
            DO_MFMAS(b0, b1)
        }
    }
    // ---- tap 8: drain with descending counted waits, no new issues ----
    {
        const int kh = 2, kw = 2;
        {   const int s = 0; VM_WAIT(6, pb0[0], pb1[0]);
            short8 b0 = pb0[0], b1 = pb1[0]; DO_MFMAS(b0, b1) }
        {   const int s = 1; VM_WAIT(4, pb0[1], pb1[1]);
            short8 b0 = pb0[1], b1 = pb1[1]; DO_MFMAS(b0, b1) }
        {   const int s = 2; VM_WAIT(2, pb0[2], pb1[2]);
            short8 b0 = pb0[2], b1 = pb1[2]; DO_MFMAS(b0, b1) }
        {   const int s = 3; VM_WAIT(0, pb0[3], pb1[3]);
            short8 b0 = pb0[3], b1 = pb1[3]; DO_MFMAS(b0, b1) }
    }
#undef DO_MFMAS

    // ---- epilogue: cross-split reduce via LDS, then direct out write ----
    __syncthreads();   // all A reads done; safe to alias with P
#pragma unroll
    for (int mt = 0; mt < 2; ++mt) {
#pragma unroll
        for (int nt = 0; nt < 2; ++nt) {
            const int row = rowl * 64 + n0 + nt * 16 + l15;   // 0..127
            // stride 36 floats (144 B): 16B-aligned float4 slots, banks spread
            *(floatx4*)(P + split * 4608 + row * 36 + mt * 16 + q * 4) = acc[mt][nt];
        }
    }
    __syncthreads();
    {
        const int x4 = (t & 7) * 4;        // 0..28
        const int row = t >> 3;            // 0..127 = rowl*64 + ocl
        const int ocl = row & 63;
        const int hh = h0 + (row >> 6);
        const int po = row * 36 + x4;
        floatx4 v = *(const floatx4*)(P + po)
                  + *(const floatx4*)(P + 4608 + po)
                  + *(const floatx4*)(P + 2 * 4608 + po)
                  + *(const floatx4*)(P + 3 * 4608 + po);
        *(floatx4*)(out + (((size_t)b * COUT + ocl) * HH + hh) * WW + x4) = v;
    }
}

extern "C" void kernel_launch(void* const* d_in, const int* in_sizes, int n_in,
                              void* d_out, int out_size, void* d_ws, size_t ws_size,
                              hipStream_t stream) {
    const float* x  = (const float*)d_in[0];
    const float* sw = (const float*)d_in[1];
    const float* sc = (const float*)d_in[2];
    float* out = (float*)d_out;
    short* W3 = (short*)d_ws;                           // 294,912 bf16 = 576 KB

    wt_kernel<<<(294912 + 255) / 256, 256, 0, stream>>>(sw, sc, W3);
    conv_kernel<<<256, 1024, 0, stream>>>(x, W3, out);
}

// Round 7
// 80.145 us; speedup vs baseline: 1.3507x; 1.0011x over previous
//
#include <hip/hip_runtime.h>

#define CINC 64
#define COUT 64
#define HH 32
#define WW 32
#define BB 16
#define NSPLIT 4
#define CPS 16            // cin per split

typedef __attribute__((ext_vector_type(8))) short short8;
typedef __attribute__((ext_vector_type(4))) float floatx4;

__device__ __forceinline__ unsigned short f2bf(float f) {
    union { float f; unsigned int u; } c; c.f = f;
    unsigned int r = (c.u + 0x7FFFu + ((c.u >> 16) & 1u)) >> 16;
    return (unsigned short)r;
}

// W3 layout (COALESCED, round-6 verified):
// [split(4)][ts(36)][half(2)][nt(2)][q(4)][l15(16)][e(8)] bf16.
// Per (split,ts,half,nt) fragment, lane (q,l15) reads shorts [lane*8..lane*8+7]
// -> one fully-contiguous 1 KB wave read.
// Logical element: ts=tap*4+s, oc=half*32+nt*16+l15, cin=split*16+s*4+q, g=e.
__global__ __launch_bounds__(256) void wt_kernel(const float* __restrict__ sw,
                                                 const float* __restrict__ sc,
                                                 short* __restrict__ W3) {
    int idx = blockIdx.x * blockDim.x + threadIdx.x;
    const int total = NSPLIT * 36 * 2 * 2 * 4 * 16 * 8;   // 294,912
    if (idx >= total) return;
    int e    = idx & 7;
    int l15  = (idx >> 3) & 15;
    int q    = (idx >> 7) & 3;
    int nt   = (idx >> 9) & 1;
    int half = (idx >> 10) & 1;
    int tsid = idx >> 11;            // 0..143 = split*36 + ts
    int ts   = tsid % 36;
    int split = tsid / 36;
    int s = ts & 3, tap = ts >> 2;
    int oc = half * 32 + nt * 16 + l15;
    int cin = split * CPS + s * 4 + q;
    int g = e;
    int kh = tap / 3, kw = tap % 3;
    float w = sw[(((oc * CINC + cin) * 8 + g) * 3 + kh) * 3 + kw] * sc[oc * CINC + cin];
    W3[idx] = (short)f2bf(w);
}

// Counted waits tied to the regs being consumed: the consumer's operands are
// OUTPUTS of the wait-asm -> true data dep, cannot be hoisted above the wait
// (rounds 5/6 proved this mechanism correct for vmcnt; rule-18's failure mode
// was early-clobber on the load, not tied operands on the wait).
#define VM_WAIT(N, a, b) asm volatile("s_waitcnt vmcnt(" #N ")" : "+v"(a), "+v"(b))
#define LG_WAIT(N, a, b) asm volatile("s_waitcnt lgkmcnt(" #N ")" : "+v"(a), "+v"(b))
// Issue one step's two B-fragment loads (nt=0 at p, nt=1 at p+1024 B).
#define B_ISSUE(a, b, p)                                            \
    asm volatile("global_load_dwordx4 %0, %2, off\n\t"              \
                 "global_load_dwordx4 %1, %2, off offset:1024"      \
                 : "=&v"(a), "=&v"(b) : "v"(p))
// Issue one step's two A-fragment LDS reads (byte offsets in VGPRs; A is the
// only __shared__ object so its LDS offset base is 0).
#define A_ISSUE(d0, d1, o0, o1)                                     \
    asm volatile("ds_read_b128 %0, %2\n\t"                          \
                 "ds_read_b128 %1, %3"                              \
                 : "=&v"(d0), "=&v"(d1) : "v"(o0), "v"(o1))

// Fused bases + implicit-GEMM conv with in-block cin-split reduction.
// Grid: 256 blocks (b, row-pair). Block: 1024 thr = 16 waves = 4 waves/SIMD.
// Wave = (split = w&3, rowl = (w>>2)&1, oc-half = w>>3); mt=2, nt=2, 36 k-steps.
// B: depth-4 pinned pipeline (8 loads in flight, counted vmcnt, all consumed).
// A: depth-1 pinned pipeline — ds_read for step ts+1 issues BEFORE step ts's
// MFMAs; counted lgkmcnt(2) allows the new pair to stay in flight. Even/odd
// static register sets (no rotation moves: a reg copy from a pending ds_read
// dest would read garbage — no HW interlock on gfx9 loads).
__global__ __launch_bounds__(1024, 4) void conv_kernel(const float* __restrict__ xin,
                                                       const short* __restrict__ W3,
                                                       float* __restrict__ out) {
    __shared__ __align__(16) char smem[139264];
    short* A = (short*)smem;   // [split][r(4)][x(34)][slot(16)][e(8)], slot = cl^(x&15)
    float* P = (float*)smem;   // [split][row(128) = rowl*64+ocl][stride 36][x(32)]

    const int mb = blockIdx.x;
    const int b = mb >> 4;
    const int h0 = (mb & 15) * 2;
    const int t = threadIdx.x;
    const int wave = t >> 6;
    const int lane = t & 63;
    const int l15 = lane & 15;
    const int q = lane >> 4;
    const int split = wave & 3;
    const int rowl = (wave >> 2) & 1;
    const int n0 = (wave >> 3) * 32;

    // ---- B pipeline prologue: issue steps 0..3 (hides under staging) ----
    const short* bp = W3 + (size_t)split * 73728 + (size_t)(wave >> 3) * 1024
                      + lane * 8;
    short8 pb0[4], pb1[4];
#pragma unroll
    for (int g = 0; g < 4; ++g) {
        B_ISSUE(pb0[g], pb1[g], bp);
        bp += 2048;
    }

    // ---- stage A: closed-form uniform cubic B-spline bases -> bf16 LDS ----
    for (int u = t; u < 4 * 34 * CINC; u += 1024) {
        int x34 = u % 34;
        int rc = u / 34;                 // 0..255
        int c6 = rc & 63;                // cin 0..63
        int r = rc >> 6;
        int sp = c6 >> 4;                // which split's tile
        int cl = c6 & 15;
        int y = h0 + r;
        float v = 0.0f;
        if (y >= 1 && y <= HH && x34 >= 1 && x34 <= WW)
            v = xin[((b * CINC + c6) * HH + (y - 1)) * WW + (x34 - 1)];
        float sv = fmaf(v, 2.5f, 5.5f);               // (v + 2.2) / 0.4
        float cf = floorf(sv);
        int c = (int)cf;
        float f = sv - cf;
        float f2 = f * f, f3 = f2 * f;
        float omf = 1.0f - f;
        float w0 = f3 * (1.0f / 6.0f);
        float w1 = (1.0f + 3.0f * f + 3.0f * f2 - 3.0f * f3) * (1.0f / 6.0f);
        float w2 = (4.0f - 6.0f * f2 + 3.0f * f3) * (1.0f / 6.0f);
        float w3 = (omf * omf * omf) * (1.0f / 6.0f);
        short o8[8];
#pragma unroll
        for (int j = 0; j < 8; ++j) {
            float bj = (j == c) ? w0 : (j == c - 1) ? w1 : (j == c - 2) ? w2
                       : (j == c - 3) ? w3 : 0.0f;
            o8[j] = (short)f2bf(bj);
        }
        *(int4*)&A[sp * 17408 + (r * 34 + x34) * 128 + ((cl ^ (x34 & 15)) * 8)] =
            *(const int4*)o8;
    }
    __syncthreads();

    floatx4 acc[2][2];
#pragma unroll
    for (int mt = 0; mt < 2; ++mt)
#pragma unroll
        for (int nt = 0; nt < 2; ++nt) acc[mt][nt] = (floatx4)0.f;

    const int abase = split * 17408;

    // A-fragment LDS byte offset for global step ts_, sub-tile mt.
    // All ts_-derived terms are compile-time in the unrolled loop.
    auto AOFF = [&](int ts_, int mt) -> unsigned {
        const int tap_ = ts_ >> 2, s_ = ts_ & 3;
        const int kh_ = tap_ / 3, kw_ = tap_ % 3;
        const int xi = mt * 16 + l15 + kw_;
        return (unsigned)(2 * (abase + ((rowl + kh_) * 34 + xi) * 128 +
                               (((s_ * 4 + q) ^ (xi & 15)) * 8)));
    };

    // ---- A pipeline prologue: issue step 0's fragments (post-barrier) ----
    short8 aE0, aE1, aO0, aO1;
    {
        unsigned o0 = AOFF(0, 0), o1 = AOFF(0, 1);
        A_ISSUE(aE0, aE1, o0, o1);
    }

#define DO_MFMAS(A0, A1, B0, B1)                                                  \
    acc[0][0] = __builtin_amdgcn_mfma_f32_16x16x32_bf16(A0, B0, acc[0][0], 0,0,0); \
    acc[0][1] = __builtin_amdgcn_mfma_f32_16x16x32_bf16(A0, B1, acc[0][1], 0,0,0); \
    acc[1][0] = __builtin_amdgcn_mfma_f32_16x16x32_bf16(A1, B0, acc[1][0], 0,0,0); \
    acc[1][1] = __builtin_amdgcn_mfma_f32_16x16x32_bf16(A1, B1, acc[1][1], 0,0,0);

    // ---- main loop: 36 steps; B depth-4 + A depth-1, both asm-pinned ----
#pragma unroll
    for (int ts = 0; ts < 36; ++ts) {
        const int s = ts & 3;
        short8 b0, b1;
        if (ts < 32) {                       // steady state: wait oldest pair, reissue
            VM_WAIT(6, pb0[s], pb1[s]);
            b0 = pb0[s]; b1 = pb1[s];
            B_ISSUE(pb0[s], pb1[s], bp);
            bp += 2048;
        } else if (ts == 32) { VM_WAIT(6, pb0[0], pb1[0]); b0 = pb0[0]; b1 = pb1[0]; }
        else if   (ts == 33) { VM_WAIT(4, pb0[1], pb1[1]); b0 = pb0[1]; b1 = pb1[1]; }
        else if   (ts == 34) { VM_WAIT(2, pb0[2], pb1[2]); b0 = pb0[2]; b1 = pb1[2]; }
        else                 { VM_WAIT(0, pb0[3], pb1[3]); b0 = pb0[3]; b1 = pb1[3]; }

        if ((ts & 1) == 0) {
            // even: consume aE (issued at ts-1 / prologue), prefetch ts+1 -> aO
            {
                unsigned o0 = AOFF(ts + 1, 0), o1 = AOFF(ts + 1, 1);
                A_ISSUE(aO0, aO1, o0, o1);
            }
            LG_WAIT(2, aE0, aE1);            // allow the just-issued pair in flight
            DO_MFMAS(aE0, aE1, b0, b1)
        } else if (ts < 35) {
            // odd: consume aO, prefetch ts+1 -> aE
            {
                unsigned o0 = AOFF(ts + 1, 0), o1 = AOFF(ts + 1, 1);
                A_ISSUE(aE0, aE1, o0, o1);
            }
            LG_WAIT(2, aO0, aO1);
            DO_MFMAS(aO0, aO1, b0, b1)
        } else {
            // ts = 35: last step, nothing to prefetch, drain lgkm
            LG_WAIT(0, aO0, aO1);
            DO_MFMAS(aO0, aO1, b0, b1)
        }
    }
#undef DO_MFMAS

    // ---- epilogue: cross-split reduce via LDS, then direct out write ----
    __syncthreads();   // all A reads done; safe to alias with P
#pragma unroll
    for (int mt = 0; mt < 2; ++mt) {
#pragma unroll
        for (int nt = 0; nt < 2; ++nt) {
            const int row = rowl * 64 + n0 + nt * 16 + l15;   // 0..127
            // stride 36 floats (144 B): 16B-aligned float4 slots, banks spread
            *(floatx4*)(P + split * 4608 + row * 36 + mt * 16 + q * 4) = acc[mt][nt];
        }
    }
    __syncthreads();
    {
        const int x4 = (t & 7) * 4;        // 0..28
        const int row = t >> 3;            // 0..127 = rowl*64 + ocl
        const int ocl = row & 63;
        const int hh = h0 + (row >> 6);
        const int po = row * 36 + x4;
        floatx4 v = *(const floatx4*)(P + po)
                  + *(const floatx4*)(P + 4608 + po)
                  + *(const floatx4*)(P + 2 * 4608 + po)
                  + *(const floatx4*)(P + 3 * 4608 + po);
        *(floatx4*)(out + (((size_t)b * COUT + ocl) * HH + hh) * WW + x4) = v;
    }
}

extern "C" void kernel_launch(void* const* d_in, const int* in_sizes, int n_in,
                              void* d_out, int out_size, void* d_ws, size_t ws_size,
                              hipStream_t stream) {
    const float* x  = (const float*)d_in[0];
    const float* sw = (const float*)d_in[1];
    const float* sc = (const float*)d_in[2];
    float* out = (float*)d_out;
    short* W3 = (short*)d_ws;                           // 294,912 bf16 = 576 KB

    wt_kernel<<<(294912 + 255) / 256, 256, 0, stream>>>(sw, sc, W3);
    conv_kernel<<<256, 1024, 0, stream>>>(x, W3, out);
}